// Round 13
// baseline (1297.861 us; speedup 1.0000x reference)
//
#include <hip/hip_runtime.h>
#include <hip/hip_fp16.h>

#define NN 20000
#define EE 320000
#define NB2 5000     // NN/4 buckets (4 nodes each)
#define BCAP2 128    // capacity (mean 64; Poisson max over 5000 buckets ~ 104)

typedef _Float16 f16;
typedef f16  f16x8 __attribute__((ext_vector_type(8)));
typedef float f32x4 __attribute__((ext_vector_type(4)));

__device__ __forceinline__ float silu_f(float x) {
    return x / (1.0f + __expf(-x));
}

// ---------------- Kernel 1: node up-projection (16 nodes/block) ----------------
__global__ __launch_bounds__(256) void up_kernel(
    const float* __restrict__ nf, const float* __restrict__ Wus,
    const float* __restrict__ Wuv, float* __restrict__ up, int dmajor)
{
    __shared__ float sWs[64 * 64];
    __shared__ float sWv[64 * 64];
    int tid = threadIdx.x;
    for (int i = tid; i < 64 * 64; i += 256) { sWs[i] = Wus[i]; sWv[i] = Wuv[i]; }
    __syncthreads();
    int lane = tid & 63, wv = tid >> 6;
    for (int it = 0; it < 4; it++) {
        int n = blockIdx.x * 16 + wv * 4 + it;
        const float* row = nf + (size_t)n * 256;
        float s  = row[lane];
        float v0 = row[64 + lane * 3 + 0];
        float v1 = row[64 + lane * 3 + 1];
        float v2 = row[64 + lane * 3 + 2];
        float as = 0.f, a0 = 0.f, a1 = 0.f, a2 = 0.f;
        #pragma unroll 8
        for (int m = 0; m < 64; m++) {
            float sm = __shfl(s, m);
            float b0 = __shfl(v0, m), b1 = __shfl(v1, m), b2 = __shfl(v2, m);
            float w_s = sWs[m * 64 + lane];
            float w_v = sWv[m * 64 + lane];
            as += sm * w_s;
            a0 += b0 * w_v; a1 += b1 * w_v; a2 += b2 * w_v;
        }
        float* o = up + (size_t)n * 256;
        if (dmajor) {
            o[lane]       = as * 0.125f;
            o[64  + lane] = a0 * 0.125f;
            o[128 + lane] = a1 * 0.125f;
            o[192 + lane] = a2 * 0.125f;
        } else {
            o[lane] = as * 0.125f;
            o[64 + lane * 3 + 0] = a0 * 0.125f;
            o[64 + lane * 3 + 1] = a1 * 0.125f;
            o[64 + lane * 3 + 2] = a2 * 0.125f;
        }
    }
}

// ---------------- MLP weight packing into MFMA B-fragment order ----------------
__global__ __launch_bounds__(256) void pack_kernel(
    const float* __restrict__ w1, const float* __restrict__ w2,
    const float* __restrict__ w3, const float* __restrict__ wo,
    f16* __restrict__ wp)
{
    int idx = blockIdx.x * 256 + threadIdx.x;   // 13*256 = 3328 >= 52*64
    if (idx >= 52 * 64) return;
    int frag = idx >> 6, lane = idx & 63;
    int col = lane & 15, kg = lane >> 4;
    f16x8 pv;
    if (frag < 4) {
        int t = frag;
        #pragma unroll
        for (int i = 0; i < 8; i++) {
            int k = kg * 8 + i;
            pv[i] = (k < 8) ? (f16)w1[k * 64 + t * 16 + col] : (f16)0.f;
        }
    } else if (frag < 12) {
        int f = frag - 4, t = f >> 1, h = f & 1;
        #pragma unroll
        for (int i = 0; i < 8; i++) {
            int k = h * 32 + kg * 8 + i;
            pv[i] = (f16)w2[k * 64 + t * 16 + col];
        }
    } else if (frag < 20) {
        int f = frag - 12, t = f >> 1, h = f & 1;
        #pragma unroll
        for (int i = 0; i < 8; i++) {
            int k = h * 32 + kg * 8 + i;
            pv[i] = (f16)w3[k * 64 + t * 16 + col];
        }
    } else {
        int f = frag - 20, t = f >> 1, h = f & 1;
        #pragma unroll
        for (int i = 0; i < 8; i++) {
            int k = h * 32 + kg * 8 + i;
            pv[i] = (f16)wo[k * 256 + t * 16 + col];
        }
    }
    *(f16x8*)(wp + (size_t)idx * 8) = pv;
}

// ---------------- Node weight packing (down + per-specie skip), scales folded ----
__global__ __launch_bounds__(256) void pack2_kernel(
    const float* __restrict__ Wds, const float* __restrict__ Wdv,
    const float* __restrict__ Wss, const float* __restrict__ Wsv,
    f16* __restrict__ wp2)
{
    int idx = blockIdx.x * 256 + threadIdx.x;   // 42*256 >= 168*64
    if (idx >= 168 * 64) return;
    int frag = idx >> 6, lane = idx & 63;
    int col = lane & 15, kg = lane >> 4;
    const float S_d = 0.25f * 0.08838834764831845f;
    const float S_k = 0.125f;
    f16x8 pv;
    if (frag < 32) {
        int t = frag >> 2, kf = frag & 3;
        #pragma unroll
        for (int i = 0; i < 8; i++) {
            int k = kf * 32 + kg * 8 + i;
            pv[i] = (f16)(Wds[k * 128 + t * 16 + col] * S_d);
        }
    } else if (frag < 48) {
        int f = frag - 32; int t = f >> 2, kf = f & 3;
        #pragma unroll
        for (int i = 0; i < 8; i++) {
            int k = kf * 32 + kg * 8 + i;
            pv[i] = (f16)(Wdv[k * 64 + t * 16 + col] * S_d);
        }
    } else if (frag < 128) {
        int f = frag - 48; int sp = f >> 4; int t = (f & 15) >> 1; int kf = f & 1;
        #pragma unroll
        for (int i = 0; i < 8; i++) {
            int k = kf * 32 + kg * 8 + i;
            pv[i] = (f16)(Wss[((size_t)sp * 64 + k) * 128 + t * 16 + col] * S_k);
        }
    } else {
        int f = frag - 128; int sp = f >> 3; int t = (f & 7) >> 1; int kf = f & 1;
        #pragma unroll
        for (int i = 0; i < 8; i++) {
            int k = kf * 32 + kg * 8 + i;
            pv[i] = (f16)(Wsv[((size_t)sp * 64 + k) * 64 + t * 16 + col] * S_k);
        }
    }
    *(f16x8*)(wp2 + (size_t)idx * 8) = pv;
}

// ---------------- Bucketing: edge -> bucket (rcv>>2) list ----------------
__global__ void bucket_kernel(const int* __restrict__ rcv,
                              int* __restrict__ cnt, int* __restrict__ list)
{
    int e = blockIdx.x * 256 + threadIdx.x;
    int r = rcv[e];
    if ((unsigned)r >= (unsigned)NN) return;
    int b = r >> 2;
    int pos = atomicAdd(&cnt[b], 1);
    if (pos < BCAP2) list[b * BCAP2 + pos] = e;
}

// ---------------- Kernel 2: bucketed MFMA MLP + LDS-aggregated gather (4 nodes) --
// Block = 1 bucket of 4 nodes, ~64 edges. 48 KiB LDS -> 3 blocks/CU (round-11
// geometry). Waves run the MFMA MLP on 16 gathered edges, then ds-add messages
// into an 8 KB block-shared f32 accumulator. ZERO global atomics.
__global__ __launch_bounds__(256) void mlp_gather(
    const float* __restrict__ radial, const f16* __restrict__ wp,
    const int* __restrict__ senders, const int* __restrict__ receivers,
    const float* __restrict__ vectors, const float* __restrict__ up2,
    const int* __restrict__ cnt, const int* __restrict__ list,
    f16* __restrict__ agg)
{
    __shared__ float acc[4 * 512];     // 8 KB block accumulator (f32)
    __shared__ f16 mlpbuf[4 * 5120];   // 40 KB: per wave act(1024)|outT(4096)
    int tid = threadIdx.x, lane = tid & 63, w = tid >> 6;
    int b = blockIdx.x;
    for (int i = tid; i < 4 * 512; i += 256) acc[i] = 0.f;
    __syncthreads();
    int count = cnt[b]; if (count > BCAP2) count = BCAP2;

    f16* actA = mlpbuf + w * 5120;
    f16* outT = actA + 1024;
    int col = lane & 15, kg = lane >> 4;
    const f32x4 zero = {0.f, 0.f, 0.f, 0.f};
    const float SQ3 = 1.7320508075688772f;

    #define LDB(fr) (*(const f16x8*)(wp + ((size_t)(fr) * 64 + lane) * 8))
    #define LDA(buf, h) (*(const f16x8*)((buf) + (lane & 15) * 64 + \
                        (((kg * 8) + (h) * 32) ^ (((lane & 15) & 7) << 3))))
    #define STACT(buf, a4, SC)                                             \
        _Pragma("unroll")                                                  \
        for (int t = 0; t < 4; t++) {                                      \
            _Pragma("unroll")                                              \
            for (int r = 0; r < 4; r++) {                                  \
                int row = kg * 4 + r;                                      \
                int c   = t * 16 + col;                                    \
                float x = a4[t][r] * (SC);                                 \
                (buf)[row * 64 + (c ^ ((row & 7) << 3))] = (f16)silu_f(x); \
            }                                                              \
        }

    for (int base = w * 16; base < count; base += 64) {
        int myE = -1;
        if (lane < 16 && base + lane < count) myE = list[b * BCAP2 + base + lane];

        // ---- layer 1: 8 -> 64 (K zero-padded to 32) ----
        {
            f16x8 a;
            if (lane < 16 && myE >= 0) {
                const float* rr = radial + (size_t)myE * 8;
                float4 ra = *(const float4*)rr;
                float4 rb = *(const float4*)(rr + 4);
                a[0] = (f16)ra.x; a[1] = (f16)ra.y; a[2] = (f16)ra.z; a[3] = (f16)ra.w;
                a[4] = (f16)rb.x; a[5] = (f16)rb.y; a[6] = (f16)rb.z; a[7] = (f16)rb.w;
            } else {
                #pragma unroll
                for (int i = 0; i < 8; i++) a[i] = (f16)0.f;
            }
            f32x4 a4[4];
            #pragma unroll
            for (int t = 0; t < 4; t++)
                a4[t] = __builtin_amdgcn_mfma_f32_16x16x32_f16(a, LDB(t), zero, 0, 0, 0);
            STACT(actA, a4, 0.35355339059327373f)
        }
        // ---- layer 2 (in-place: frags loaded to regs before stores) ----
        {
            f16x8 a0 = LDA(actA, 0), a1 = LDA(actA, 1);
            f32x4 a4[4];
            #pragma unroll
            for (int t = 0; t < 4; t++) {
                a4[t] = __builtin_amdgcn_mfma_f32_16x16x32_f16(a0, LDB(4 + t * 2), zero, 0, 0, 0);
                a4[t] = __builtin_amdgcn_mfma_f32_16x16x32_f16(a1, LDB(5 + t * 2), a4[t], 0, 0, 0);
            }
            STACT(actA, a4, 0.125f)
        }
        // ---- layer 3 ----
        {
            f16x8 a0 = LDA(actA, 0), a1 = LDA(actA, 1);
            f32x4 a4[4];
            #pragma unroll
            for (int t = 0; t < 4; t++) {
                a4[t] = __builtin_amdgcn_mfma_f32_16x16x32_f16(a0, LDB(12 + t * 2), zero, 0, 0, 0);
                a4[t] = __builtin_amdgcn_mfma_f32_16x16x32_f16(a1, LDB(13 + t * 2), a4[t], 0, 0, 0);
            }
            STACT(actA, a4, 0.125f)
        }
        // ---- output layer: 64 -> 256 into outT ----
        {
            f16x8 a0 = LDA(actA, 0), a1 = LDA(actA, 1);
            #pragma unroll
            for (int tg = 0; tg < 4; tg++) {
                f32x4 a4[4];
                #pragma unroll
                for (int q = 0; q < 4; q++) {
                    int t = tg * 4 + q;
                    a4[q] = __builtin_amdgcn_mfma_f32_16x16x32_f16(a0, LDB(20 + t * 2), zero, 0, 0, 0);
                    a4[q] = __builtin_amdgcn_mfma_f32_16x16x32_f16(a1, LDB(21 + t * 2), a4[q], 0, 0, 0);
                }
                #pragma unroll
                for (int q = 0; q < 4; q++) {
                    int t = tg * 4 + q;
                    #pragma unroll
                    for (int r = 0; r < 4; r++) {
                        int row = kg * 4 + r;
                        int c   = t * 16 + col;
                        outT[row * 256 + (c ^ ((row & 7) << 3))] = (f16)(a4[q][r] * 0.125f);
                    }
                }
            }
        }

        // ---- message phase: ds-add into block accumulator ----
        int i2 = (lane & 31) * 2;
        bool lo = (lane < 32);
        for (int el = 0; el < 16; el++) {
            int e = __shfl(myE, el);
            if (e < 0) continue;
            int snd = senders[e];
            int rl  = receivers[e] - b * 4;
            if ((unsigned)snd >= (unsigned)NN) snd = 0;
            if ((unsigned)rl >= 4u) rl = 0;
            float vx = vectors[(size_t)e * 3 + 0];
            float vy = vectors[(size_t)e * 3 + 1];
            float vz = vectors[(size_t)e * 3 + 2];
            float l2 = vx * vx + vy * vy + vz * vz;
            float il   = (l2 > 0.f) ? rsqrtf(l2) : 0.f;
            float mask = (l2 > 0.f) ? 1.f : 0.f;

            int sw = (el & 7) << 3;
            const f16* orow = outT + el * 256;
            float2 mA = __half22float2(*(const __half2*)(orow + ((i2      ) ^ sw)));
            float2 mB = __half22float2(*(const __half2*)(orow + ((64 + i2) ^ sw)));
            float2 mC = __half22float2(*(const __half2*)(orow + ((128 + i2) ^ sw)));
            float2 mD = __half22float2(*(const __half2*)(orow + ((192 + i2) ^ sw)));
            float mA0 = mA.x * mask, mA1 = mA.y * mask;
            float mB0 = mB.x * mask, mB1 = mB.y * mask;
            float mC0 = mC.x * mask, mC1 = mC.y * mask;
            float mD0 = mD.x * mask, mD1 = mD.y * mask;

            const float* u = up2 + (size_t)snd * 256;
            float2 s2  = *(const float2*)(u + i2);
            float2 ex2 = *(const float2*)(u + 64  + i2);
            float2 ey2 = *(const float2*)(u + 128 + i2);
            float2 ez2 = *(const float2*)(u + 192 + i2);

            float tps0 = (ex2.x * vx + ey2.x * vy + ez2.x * vz) * il;
            float tps1 = (ex2.y * vx + ey2.y * vy + ez2.y * vz) * il;
            float yx = SQ3 * vx * il, yy = SQ3 * vy * il, yz = SQ3 * vz * il;

            float v0x = lo ? s2.x * mA0 : tps0 * mB0;
            float v0y = lo ? s2.y * mA1 : tps1 * mB1;
            float v1x = lo ? ex2.x * mC0 : ey2.x * mC0;
            float v1y = lo ? ex2.y * mC1 : ey2.y * mC1;
            float v2x = lo ? ez2.x * mC0 : s2.x * yx * mD0;
            float v2y = lo ? ez2.y * mC1 : s2.y * yx * mD1;
            float v3x = lo ? s2.x * yy * mD0 : s2.x * yz * mD0;
            float v3y = lo ? s2.y * yy * mD1 : s2.y * yz * mD1;

            float* arow = acc + rl * 512;
            int f0 = 2 * lane;
            atomicAdd(arow + f0,           v0x);
            atomicAdd(arow + f0 + 1,       v0y);
            atomicAdd(arow + 128 + f0,     v1x);
            atomicAdd(arow + 128 + f0 + 1, v1y);
            atomicAdd(arow + 256 + f0,     v2x);
            atomicAdd(arow + 256 + f0 + 1, v2y);
            atomicAdd(arow + 384 + f0,     v3x);
            atomicAdd(arow + 384 + f0 + 1, v3y);
        }
    }
    __syncthreads();
    // ---- writeout: 4 rows x 512 f16, coalesced (2048 vals = 256 x 8) ----
    {
        int pos = tid * 8;
        f16x8 v;
        #pragma unroll
        for (int i = 0; i < 8; i++) v[i] = (f16)acc[pos + i];
        *(f16x8*)(agg + (size_t)b * 2048 + pos) = v;
    }
    #undef LDB
    #undef LDA
    #undef STACT
}

// ---------------- Kernel 4: MFMA node tail (no LDS, no shuffles) ----------------
__global__ __launch_bounds__(256) void node_mfma(
    const float* __restrict__ nf, const int* __restrict__ specie,
    const f16* __restrict__ wp2, const f16* __restrict__ agg,
    float* __restrict__ out)
{
    int tid = threadIdx.x, lane = tid & 63, w = tid >> 6;
    int n0 = (blockIdx.x * 4 + w) * 16;
    if (n0 >= NN) return;
    int col = lane & 15, kg = lane >> 4;
    int myn = n0 + col;
    int mysp = specie[myn];
    if ((unsigned)mysp >= 5u) mysp = 0;
    const f32x4 zero = {0.f, 0.f, 0.f, 0.f};
    const f16x8 zv = {};

    #define LDB2(fr) (*(const f16x8*)(wp2 + ((size_t)(fr) * 64 + lane) * 8))

    f32x4 accs[8];
    #pragma unroll
    for (int t = 0; t < 8; t++) accs[t] = zero;
    #pragma unroll
    for (int kf = 0; kf < 4; kf++) {
        f16x8 a = *(const f16x8*)(agg + (size_t)myn * 512 + kf * 32 + kg * 8);
        #pragma unroll
        for (int t = 0; t < 8; t++)
            accs[t] = __builtin_amdgcn_mfma_f32_16x16x32_f16(a, LDB2(t * 4 + kf), accs[t], 0, 0, 0);
    }
    #pragma unroll
    for (int kf = 0; kf < 2; kf++) {
        const float* base = nf + (size_t)myn * 256 + kf * 32 + kg * 8;
        float4 x0 = *(const float4*)(base);
        float4 x1 = *(const float4*)(base + 4);
        f16x8 a;
        a[0] = (f16)x0.x; a[1] = (f16)x0.y; a[2] = (f16)x0.z; a[3] = (f16)x0.w;
        a[4] = (f16)x1.x; a[5] = (f16)x1.y; a[6] = (f16)x1.z; a[7] = (f16)x1.w;
        #pragma unroll
        for (int sp = 0; sp < 5; sp++) {
            f16x8 am = (mysp == sp) ? a : zv;
            #pragma unroll
            for (int t = 0; t < 8; t++)
                accs[t] = __builtin_amdgcn_mfma_f32_16x16x32_f16(am, LDB2(48 + sp * 16 + t * 2 + kf), accs[t], 0, 0, 0);
        }
    }
    float gates[4][4];
    #pragma unroll
    for (int t = 0; t < 4; t++) {
        #pragma unroll
        for (int r = 0; r < 4; r++) {
            int n = n0 + kg * 4 + r;
            out[(size_t)n * 256 + t * 16 + col] = fmaxf(silu_f(accs[t][r]), 0.f);
            gates[t][r] = silu_f(accs[4 + t][r]);
        }
    }

    #pragma unroll
    for (int c = 0; c < 3; c++) {
        f32x4 accv[4];
        #pragma unroll
        for (int t = 0; t < 4; t++) accv[t] = zero;
        #pragma unroll
        for (int kf = 0; kf < 4; kf++) {
            int off = (kf < 2) ? (128 + c * 64 + kf * 32) : (320 + c * 64 + (kf - 2) * 32);
            f16x8 a = *(const f16x8*)(agg + (size_t)myn * 512 + off + kg * 8);
            #pragma unroll
            for (int t = 0; t < 4; t++)
                accv[t] = __builtin_amdgcn_mfma_f32_16x16x32_f16(a, LDB2(32 + t * 4 + kf), accv[t], 0, 0, 0);
        }
        #pragma unroll
        for (int kf = 0; kf < 2; kf++) {
            const float* base = nf + (size_t)myn * 256 + 64 + (kf * 32 + kg * 8) * 3;
            float4 q0 = *(const float4*)(base);
            float4 q1 = *(const float4*)(base + 4);
            float4 q2 = *(const float4*)(base + 8);
            float4 q3 = *(const float4*)(base + 12);
            float4 q4 = *(const float4*)(base + 16);
            float4 q5 = *(const float4*)(base + 20);
            float qa[24] = {q0.x, q0.y, q0.z, q0.w, q1.x, q1.y, q1.z, q1.w,
                            q2.x, q2.y, q2.z, q2.w, q3.x, q3.y, q3.z, q3.w,
                            q4.x, q4.y, q4.z, q4.w, q5.x, q5.y, q5.z, q5.w};
            f16x8 a;
            #pragma unroll
            for (int i = 0; i < 8; i++) a[i] = (f16)qa[i * 3 + c];
            #pragma unroll
            for (int sp = 0; sp < 5; sp++) {
                f16x8 am = (mysp == sp) ? a : zv;
                #pragma unroll
                for (int t = 0; t < 4; t++)
                    accv[t] = __builtin_amdgcn_mfma_f32_16x16x32_f16(am, LDB2(128 + sp * 8 + t * 2 + kf), accv[t], 0, 0, 0);
            }
        }
        #pragma unroll
        for (int t = 0; t < 4; t++) {
            #pragma unroll
            for (int r = 0; r < 4; r++) {
                int n = n0 + kg * 4 + r;
                out[(size_t)n * 256 + 64 + (t * 16 + col) * 3 + c] =
                    fmaxf(gates[t][r] * accv[t][r], 0.f);
            }
        }
    }
    #undef LDB2
}

// ---------------- Kernel 4b: node tail, f32 agg (fallback path) ----------------
__global__ __launch_bounds__(256) void node_kernel_f(
    const float* __restrict__ nf, const int* __restrict__ specie,
    const float* __restrict__ Wds, const float* __restrict__ Wdv,
    const float* __restrict__ Wss, const float* __restrict__ Wsv,
    const float* __restrict__ agg, float* __restrict__ out)
{
    __shared__ float sDs[128 * 128];
    __shared__ float sDv[128 * 64];
    int tid = threadIdx.x;
    for (int i = tid; i < 128 * 128; i += 256) sDs[i] = Wds[i];
    for (int i = tid; i < 128 * 64; i += 256) sDv[i] = Wdv[i];
    __syncthreads();
    int lane = tid & 63, wv = tid >> 6;
    for (int it = 0; it < 4; it++) {
        int n = blockIdx.x * 16 + wv * 4 + it;
        const float* arow = agg + (size_t)n * 512;
        const float inv_nei = 0.25f;
        float as0 = arow[lane] * inv_nei;
        float as1 = arow[64 + lane] * inv_nei;
        float av00 = arow[128 + lane] * inv_nei;
        float av01 = arow[192 + lane] * inv_nei;
        float av02 = arow[256 + lane] * inv_nei;
        float av10 = arow[320 + lane] * inv_nei;
        float av11 = arow[384 + lane] * inv_nei;
        float av12 = arow[448 + lane] * inv_nei;
        const float* row = nf + (size_t)n * 256;
        float s   = row[lane];
        float vv0 = row[64 + lane * 3 + 0];
        float vv1 = row[64 + lane * 3 + 1];
        float vv2 = row[64 + lane * 3 + 2];

        float f0 = 0.f, f1 = 0.f, fv0 = 0.f, fv1 = 0.f, fv2 = 0.f;
        #pragma unroll 8
        for (int m = 0; m < 64; m++) {
            float am = __shfl(as0, m);
            f0 += am * sDs[m * 128 + lane];
            f1 += am * sDs[m * 128 + 64 + lane];
            float b0 = __shfl(av00, m), b1 = __shfl(av01, m), b2 = __shfl(av02, m);
            float wd = sDv[m * 64 + lane];
            fv0 += b0 * wd; fv1 += b1 * wd; fv2 += b2 * wd;
        }
        #pragma unroll 8
        for (int m = 0; m < 64; m++) {
            float am = __shfl(as1, m);
            f0 += am * sDs[(64 + m) * 128 + lane];
            f1 += am * sDs[(64 + m) * 128 + 64 + lane];
            float b0 = __shfl(av10, m), b1 = __shfl(av11, m), b2 = __shfl(av12, m);
            float wd = sDv[(64 + m) * 64 + lane];
            fv0 += b0 * wd; fv1 += b1 * wd; fv2 += b2 * wd;
        }
        const float inv2m = 0.08838834764831845f;
        f0 *= inv2m; f1 *= inv2m; fv0 *= inv2m; fv1 *= inv2m; fv2 *= inv2m;

        int sp = specie[n];
        if ((unsigned)sp >= 5u) sp = 0;
        const float* Ws = Wss + (size_t)sp * 64 * 128;
        const float* Wv = Wsv + (size_t)sp * 64 * 64;
        float g0 = 0.f, g1 = 0.f, h0 = 0.f, h1 = 0.f, h2 = 0.f;
        #pragma unroll 4
        for (int m = 0; m < 64; m++) {
            float sm = __shfl(s, m);
            g0 += sm * Ws[m * 128 + lane];
            g1 += sm * Ws[m * 128 + 64 + lane];
            float b0 = __shfl(vv0, m), b1 = __shfl(vv1, m), b2 = __shfl(vv2, m);
            float wsk = Wv[m * 64 + lane];
            h0 += b0 * wsk; h1 += b1 * wsk; h2 += b2 * wsk;
        }
        f0 += g0 * 0.125f; f1 += g1 * 0.125f;
        fv0 += h0 * 0.125f; fv1 += h1 * 0.125f; fv2 += h2 * 0.125f;

        float gs   = silu_f(f0);
        float gate = silu_f(f1);
        float* orow = out + (size_t)n * 256;
        orow[lane] = fmaxf(gs, 0.f);
        orow[64 + lane * 3 + 0] = fmaxf(gate * fv0, 0.f);
        orow[64 + lane * 3 + 1] = fmaxf(gate * fv1, 0.f);
        orow[64 + lane * 3 + 2] = fmaxf(gate * fv2, 0.f);
    }
}

// ---------------- Fallback: round-3 fused edge kernel (interleaved up layout) ----------------
__global__ __launch_bounds__(256) void edge_kernel_fb(
    const float* __restrict__ vectors, const float* __restrict__ radial,
    const int* __restrict__ senders, const int* __restrict__ receivers,
    const float* __restrict__ w1, const float* __restrict__ w2,
    const float* __restrict__ w3, const float* __restrict__ wo,
    const float* __restrict__ up, float* __restrict__ agg)
{
    __shared__ __half2 hL[32 * 256];
    __shared__ float   T[16 * 256];
    __shared__ float   sVec[256 * 3];
    __shared__ int     sSnd[256];
    __shared__ int     sRcv[256];

    int tid = threadIdx.x;
    int e = blockIdx.x * 256 + tid;
    int snd = senders[e];
    int rcv = receivers[e];
    if ((unsigned)snd >= (unsigned)NN) snd = 0;
    if ((unsigned)rcv >= (unsigned)NN) rcv = 0;
    float4 ra = *(const float4*)(radial + (size_t)e * 8);
    float4 rb = *(const float4*)(radial + (size_t)e * 8 + 4);
    float vx = vectors[(size_t)e * 3 + 0];
    float vy = vectors[(size_t)e * 3 + 1];
    float vz = vectors[(size_t)e * 3 + 2];
    sSnd[tid] = snd; sRcv[tid] = rcv;
    sVec[tid * 3 + 0] = vx; sVec[tid * 3 + 1] = vy; sVec[tid * 3 + 2] = vz;
    float len2 = vx * vx + vy * vy + vz * vz;
    float mask = (len2 > 0.f) ? 1.f : 0.f;

    {
        float a[64];
        #pragma unroll
        for (int j = 0; j < 64; j++) {
            float acc = ra.x * w1[j]       + ra.y * w1[64 + j]
                      + ra.z * w1[128 + j] + ra.w * w1[192 + j]
                      + rb.x * w1[256 + j] + rb.y * w1[320 + j]
                      + rb.z * w1[384 + j] + rb.w * w1[448 + j];
            a[j] = silu_f(acc * 0.35355339059327373f);
        }
        #pragma unroll
        for (int jp = 0; jp < 32; jp++)
            hL[jp * 256 + tid] = __floats2half2_rn(a[2 * jp], a[2 * jp + 1]);
    }
    {
        float acc[64];
        #pragma unroll
        for (int j = 0; j < 64; j++) acc[j] = 0.f;
        #pragma unroll 2
        for (int kp = 0; kp < 32; kp++) {
            float2 hf = __half22float2(hL[kp * 256 + tid]);
            const float* wr0 = w2 + (size_t)(2 * kp) * 64;
            const float* wr1 = w2 + (size_t)(2 * kp + 1) * 64;
            #pragma unroll
            for (int j = 0; j < 64; j++) acc[j] += hf.x * wr0[j] + hf.y * wr1[j];
        }
        #pragma unroll
        for (int jp = 0; jp < 32; jp++)
            hL[jp * 256 + tid] = __floats2half2_rn(silu_f(acc[2 * jp] * 0.125f),
                                                   silu_f(acc[2 * jp + 1] * 0.125f));
    }
    {
        float acc[64];
        #pragma unroll
        for (int j = 0; j < 64; j++) acc[j] = 0.f;
        #pragma unroll 2
        for (int kp = 0; kp < 32; kp++) {
            float2 hf = __half22float2(hL[kp * 256 + tid]);
            const float* wr0 = w3 + (size_t)(2 * kp) * 64;
            const float* wr1 = w3 + (size_t)(2 * kp + 1) * 64;
            #pragma unroll
            for (int j = 0; j < 64; j++) acc[j] += hf.x * wr0[j] + hf.y * wr1[j];
        }
        #pragma unroll
        for (int jp = 0; jp < 32; jp++)
            hL[jp * 256 + tid] = __floats2half2_rn(silu_f(acc[2 * jp] * 0.125f),
                                                   silu_f(acc[2 * jp + 1] * 0.125f));
    }

    int lane  = tid & 63;
    int wbase = tid & 192;
    int f = lane & 15;
    int g = lane >> 4;

    #define COMPUTE_CHUNK(c, ao)                                                \
        {                                                                       \
            _Pragma("unroll")                                                   \
            for (int j = 0; j < 16; j++) ao[j] = 0.f;                           \
            _Pragma("unroll 4")                                                 \
            for (int kp = 0; kp < 32; kp++) {                                   \
                float2 hf = __half22float2(hL[kp * 256 + tid]);                 \
                const float* wr0 = wo + (size_t)(2 * kp) * 256 + (c) * 16;      \
                const float* wr1 = wo + (size_t)(2 * kp + 1) * 256 + (c) * 16;  \
                _Pragma("unroll")                                               \
                for (int j = 0; j < 16; j++)                                    \
                    ao[j] += hf.x * wr0[j] + hf.y * wr1[j];                     \
            }                                                                   \
            _Pragma("unroll")                                                   \
            for (int j = 0; j < 16; j++) ao[j] *= 0.125f * mask;                \
        }

    #define WRITE_T(ao)                                                         \
        __syncthreads();                                                        \
        _Pragma("unroll")                                                       \
        for (int j = 0; j < 16; j++) T[j * 256 + (tid ^ (2 * j))] = ao[j];      \
        __syncthreads();

    for (int c = 0; c < 4; c++) {
        float ao[16];
        COMPUTE_CHUNK(c, ao)
        WRITE_T(ao)
        for (int el = 0; el < 16; el++) {
            int col = wbase + el * 4 + g;
            int s_ = sSnd[col], rc = sRcv[col];
            float mx = T[f * 256 + (col ^ (2 * f))];
            int jf = c * 16 + f;
            atomicAdd(agg + (size_t)rc * 512 + jf, up[(size_t)s_ * 256 + jf] * mx);
        }
    }
    for (int c = 4; c < 8; c++) {
        float ao[16];
        COMPUTE_CHUNK(c, ao)
        WRITE_T(ao)
        for (int el = 0; el < 16; el++) {
            int col = wbase + el * 4 + g;
            int s_ = sSnd[col], rc = sRcv[col];
            float wx = sVec[col * 3 + 0], wy = sVec[col * 3 + 1], wz = sVec[col * 3 + 2];
            float l2 = wx * wx + wy * wy + wz * wz;
            float il = (l2 > 0.f) ? rsqrtf(l2) : 0.f;
            float mx = T[f * 256 + (col ^ (2 * f))];
            int m = (c - 4) * 16 + f;
            const float* ev = up + (size_t)s_ * 256 + 64 + m * 3;
            float dot = ev[0] * wx + ev[1] * wy + ev[2] * wz;
            atomicAdd(agg + (size_t)rc * 512 + 64 + m, dot * il * mx);
        }
    }
    for (int c = 8; c < 12; c++) {
        float ao[16];
        COMPUTE_CHUNK(c, ao)
        WRITE_T(ao)
        for (int el = 0; el < 16; el++) {
            int col = wbase + el * 4 + g;
            int s_ = sSnd[col], rc = sRcv[col];
            float mx = T[f * 256 + (col ^ (2 * f))];
            int m = (c - 8) * 16 + f;
            const float* ev = up + (size_t)s_ * 256 + 64 + m * 3;
            float* ag = agg + (size_t)rc * 512 + 128 + m;
            atomicAdd(ag + 0,   ev[0] * mx);
            atomicAdd(ag + 64,  ev[1] * mx);
            atomicAdd(ag + 128, ev[2] * mx);
        }
    }
    for (int c = 12; c < 16; c++) {
        float ao[16];
        COMPUTE_CHUNK(c, ao)
        WRITE_T(ao)
        for (int el = 0; el < 16; el++) {
            int col = wbase + el * 4 + g;
            int s_ = sSnd[col], rc = sRcv[col];
            float wx = sVec[col * 3 + 0], wy = sVec[col * 3 + 1], wz = sVec[col * 3 + 2];
            float l2 = wx * wx + wy * wy + wz * wz;
            float il = (l2 > 0.f) ? rsqrtf(l2) : 0.f;
            float mx = T[f * 256 + (col ^ (2 * f))];
            int m = (c - 12) * 16 + f;
            float sc = up[(size_t)s_ * 256 + m] * 1.7320508075688772f * il * mx;
            float* ag = agg + (size_t)rc * 512 + 320 + m;
            atomicAdd(ag + 0,   sc * wx);
            atomicAdd(ag + 64,  sc * wy);
            atomicAdd(ag + 128, sc * wz);
        }
    }
    #undef COMPUTE_CHUNK
    #undef WRITE_T
}

extern "C" void kernel_launch(void* const* d_in, const int* in_sizes, int n_in,
                              void* d_out, int out_size, void* d_ws, size_t ws_size,
                              hipStream_t stream) {
    const float* vectors     = (const float*)d_in[0];
    const float* node_feats  = (const float*)d_in[1];
    const int*   node_specie = (const int*)d_in[2];
    const float* radial      = (const float*)d_in[3];
    const int*   senders     = (const int*)d_in[4];
    const int*   receivers   = (const int*)d_in[5];
    const float* W_up_s      = (const float*)d_in[6];
    const float* W_up_v      = (const float*)d_in[7];
    const float* mlp_w1      = (const float*)d_in[8];
    const float* mlp_w2      = (const float*)d_in[9];
    const float* mlp_w3      = (const float*)d_in[10];
    const float* mlp_wo      = (const float*)d_in[11];
    const float* W_skip_s    = (const float*)d_in[12];
    const float* W_skip_v    = (const float*)d_in[13];
    const float* W_down_s    = (const float*)d_in[14];
    const float* W_down_v    = (const float*)d_in[15];
    float* out = (float*)d_out;

    // workspace: up | agg-region (f32-sized; f16 primary / f32 fallback) | wpack | wp2 | cnt | list
    float* up   = (float*)d_ws;                      // NN*256 f32  = 20.48 MB
    float* aggf = up + (size_t)NN * 256;             // NN*512 f32  (fallback)
    f16*   aggh = (f16*)aggf;                        // NN*512 f16  (primary)
    uintptr_t wp_addr = ((uintptr_t)(aggf + (size_t)NN * 512) + 255) & ~(uintptr_t)255;
    f16* wpack = (f16*)wp_addr;                      // 52*64*8 f16  = 26.6 KB
    f16* wp2   = wpack + (size_t)52 * 64 * 8;        // 168*64*8 f16 = 172 KB
    int* cnt   = (int*)(wp2 + (size_t)168 * 64 * 8); // NB2 ints (pad to 5120)
    int* list  = cnt + 5120;                         // NB2*BCAP2 ints = 2.56 MB
    size_t required = (size_t)((uintptr_t)(list + (size_t)NB2 * BCAP2)
                               - (uintptr_t)d_ws);

    if (ws_size >= required) {
        // ---- bucketed gather (4 nodes/bucket): MFMA MLP + LDS aggregation ----
        hipMemsetAsync(cnt, 0, NB2 * sizeof(int), stream);
        pack_kernel<<<13, 256, 0, stream>>>(mlp_w1, mlp_w2, mlp_w3, mlp_wo, wpack);
        pack2_kernel<<<42, 256, 0, stream>>>(W_down_s, W_down_v, W_skip_s, W_skip_v, wp2);
        up_kernel<<<NN / 16, 256, 0, stream>>>(node_feats, W_up_s, W_up_v, up, 1);
        bucket_kernel<<<EE / 256, 256, 0, stream>>>(receivers, cnt, list);
        mlp_gather<<<NB2, 256, 0, stream>>>(radial, wpack, senders, receivers,
            vectors, up, cnt, list, aggh);
        node_mfma<<<(NN / 16 + 3) / 4, 256, 0, stream>>>(node_feats, node_specie,
            wp2, aggh, out);
    } else {
        // ---- fallback: round-3 fused atomic path (f32 agg) ----
        hipMemsetAsync(aggf, 0, (size_t)NN * 512 * sizeof(float), stream);
        up_kernel<<<NN / 16, 256, 0, stream>>>(node_feats, W_up_s, W_up_v, up, 0);
        edge_kernel_fb<<<EE / 256, 256, 0, stream>>>(
            vectors, radial, senders, receivers,
            mlp_w1, mlp_w2, mlp_w3, mlp_wo, up, aggf);
        node_kernel_f<<<NN / 16, 256, 0, stream>>>(node_feats, node_specie,
            W_down_s, W_down_v, W_skip_s, W_skip_v, aggf, out);
    }
}

// Round 14
// 320.194 us; speedup vs baseline: 4.0534x; 4.0534x over previous
//
#include <hip/hip_runtime.h>
#include <hip/hip_fp16.h>

#define NN 20000
#define EE 320000
#define BCAP3 64     // per-node capacity (mean 16; P(Poisson(16)>64) ~ 1e-20)

typedef _Float16 f16;
typedef f16  f16x8 __attribute__((ext_vector_type(8)));
typedef float f32x4 __attribute__((ext_vector_type(4)));

__device__ __forceinline__ float silu_f(float x) {
    return x / (1.0f + __expf(-x));
}

// ---------------- Kernel 1: node up-projection (16 nodes/block) ----------------
__global__ __launch_bounds__(256) void up_kernel(
    const float* __restrict__ nf, const float* __restrict__ Wus,
    const float* __restrict__ Wuv, float* __restrict__ up, int dmajor)
{
    __shared__ float sWs[64 * 64];
    __shared__ float sWv[64 * 64];
    int tid = threadIdx.x;
    for (int i = tid; i < 64 * 64; i += 256) { sWs[i] = Wus[i]; sWv[i] = Wuv[i]; }
    __syncthreads();
    int lane = tid & 63, wv = tid >> 6;
    for (int it = 0; it < 4; it++) {
        int n = blockIdx.x * 16 + wv * 4 + it;
        const float* row = nf + (size_t)n * 256;
        float s  = row[lane];
        float v0 = row[64 + lane * 3 + 0];
        float v1 = row[64 + lane * 3 + 1];
        float v2 = row[64 + lane * 3 + 2];
        float as = 0.f, a0 = 0.f, a1 = 0.f, a2 = 0.f;
        #pragma unroll 8
        for (int m = 0; m < 64; m++) {
            float sm = __shfl(s, m);
            float b0 = __shfl(v0, m), b1 = __shfl(v1, m), b2 = __shfl(v2, m);
            float w_s = sWs[m * 64 + lane];
            float w_v = sWv[m * 64 + lane];
            as += sm * w_s;
            a0 += b0 * w_v; a1 += b1 * w_v; a2 += b2 * w_v;
        }
        float* o = up + (size_t)n * 256;
        if (dmajor) {
            o[lane]       = as * 0.125f;
            o[64  + lane] = a0 * 0.125f;
            o[128 + lane] = a1 * 0.125f;
            o[192 + lane] = a2 * 0.125f;
        } else {
            o[lane] = as * 0.125f;
            o[64 + lane * 3 + 0] = a0 * 0.125f;
            o[64 + lane * 3 + 1] = a1 * 0.125f;
            o[64 + lane * 3 + 2] = a2 * 0.125f;
        }
    }
}

// ---------------- MLP weight packing into MFMA B-fragment order ----------------
__global__ __launch_bounds__(256) void pack_kernel(
    const float* __restrict__ w1, const float* __restrict__ w2,
    const float* __restrict__ w3, const float* __restrict__ wo,
    f16* __restrict__ wp)
{
    int idx = blockIdx.x * 256 + threadIdx.x;   // 13*256 >= 52*64
    if (idx >= 52 * 64) return;
    int frag = idx >> 6, lane = idx & 63;
    int col = lane & 15, kg = lane >> 4;
    f16x8 pv;
    if (frag < 4) {
        int t = frag;
        #pragma unroll
        for (int i = 0; i < 8; i++) {
            int k = kg * 8 + i;
            pv[i] = (k < 8) ? (f16)w1[k * 64 + t * 16 + col] : (f16)0.f;
        }
    } else if (frag < 12) {
        int f = frag - 4, t = f >> 1, h = f & 1;
        #pragma unroll
        for (int i = 0; i < 8; i++) {
            int k = h * 32 + kg * 8 + i;
            pv[i] = (f16)w2[k * 64 + t * 16 + col];
        }
    } else if (frag < 20) {
        int f = frag - 12, t = f >> 1, h = f & 1;
        #pragma unroll
        for (int i = 0; i < 8; i++) {
            int k = h * 32 + kg * 8 + i;
            pv[i] = (f16)w3[k * 64 + t * 16 + col];
        }
    } else {
        int f = frag - 20, t = f >> 1, h = f & 1;
        #pragma unroll
        for (int i = 0; i < 8; i++) {
            int k = h * 32 + kg * 8 + i;
            pv[i] = (f16)wo[k * 256 + t * 16 + col];
        }
    }
    *(f16x8*)(wp + (size_t)idx * 8) = pv;
}

// ---------------- Node weight packing (down + per-specie skip), scales folded ----
__global__ __launch_bounds__(256) void pack2_kernel(
    const float* __restrict__ Wds, const float* __restrict__ Wdv,
    const float* __restrict__ Wss, const float* __restrict__ Wsv,
    f16* __restrict__ wp2)
{
    int idx = blockIdx.x * 256 + threadIdx.x;   // 42*256 >= 168*64
    if (idx >= 168 * 64) return;
    int frag = idx >> 6, lane = idx & 63;
    int col = lane & 15, kg = lane >> 4;
    const float S_d = 0.25f * 0.08838834764831845f;
    const float S_k = 0.125f;
    f16x8 pv;
    if (frag < 32) {
        int t = frag >> 2, kf = frag & 3;
        #pragma unroll
        for (int i = 0; i < 8; i++) {
            int k = kf * 32 + kg * 8 + i;
            pv[i] = (f16)(Wds[k * 128 + t * 16 + col] * S_d);
        }
    } else if (frag < 48) {
        int f = frag - 32; int t = f >> 2, kf = f & 3;
        #pragma unroll
        for (int i = 0; i < 8; i++) {
            int k = kf * 32 + kg * 8 + i;
            pv[i] = (f16)(Wdv[k * 64 + t * 16 + col] * S_d);
        }
    } else if (frag < 128) {
        int f = frag - 48; int sp = f >> 4; int t = (f & 15) >> 1; int kf = f & 1;
        #pragma unroll
        for (int i = 0; i < 8; i++) {
            int k = kf * 32 + kg * 8 + i;
            pv[i] = (f16)(Wss[((size_t)sp * 64 + k) * 128 + t * 16 + col] * S_k);
        }
    } else {
        int f = frag - 128; int sp = f >> 3; int t = (f & 7) >> 1; int kf = f & 1;
        #pragma unroll
        for (int i = 0; i < 8; i++) {
            int k = kf * 32 + kg * 8 + i;
            pv[i] = (f16)(Wsv[((size_t)sp * 64 + k) * 64 + t * 16 + col] * S_k);
        }
    }
    *(f16x8*)(wp2 + (size_t)idx * 8) = pv;
}

// ---------------- Bucketing: per-NODE edge lists ----------------
__global__ void bucket_kernel(const int* __restrict__ rcv,
                              int* __restrict__ cnt, int* __restrict__ list)
{
    int e = blockIdx.x * 256 + threadIdx.x;
    int r = rcv[e];
    if ((unsigned)r >= (unsigned)NN) return;
    int pos = atomicAdd(&cnt[r], 1);
    if (pos < BCAP3) list[(size_t)r * BCAP3 + pos] = e;
}

// ---------------- Kernel 2: MFMA edge MLP -> mix (round-9 proven) ----------------
__global__ __launch_bounds__(256) void mlp_mix(
    const float* __restrict__ radial, const f16* __restrict__ wp,
    f16* __restrict__ mix)
{
    __shared__ f16 smem[4 * 6144];   // per wave: actA(1024)|actB(1024)|outT(4096)
    int tid = threadIdx.x, lane = tid & 63, w = tid >> 6;
    f16* actA = smem + w * 6144;
    f16* actB = actA + 1024;
    f16* outT = actB + 1024;
    int e0 = (blockIdx.x * 4 + w) * 16;

    int col = lane & 15;
    int kg  = lane >> 4;
    const f32x4 zero = {0.f, 0.f, 0.f, 0.f};

    #define LDB(fr) (*(const f16x8*)(wp + ((size_t)(fr) * 64 + lane) * 8))
    #define LDA(buf, h) (*(const f16x8*)((buf) + (lane & 15) * 64 + \
                        (((kg * 8) + (h) * 32) ^ (((lane & 15) & 7) << 3))))
    #define STACT(buf, acc, SC)                                            \
        _Pragma("unroll")                                                  \
        for (int t = 0; t < 4; t++) {                                      \
            _Pragma("unroll")                                              \
            for (int r = 0; r < 4; r++) {                                  \
                int row = kg * 4 + r;                                      \
                int c   = t * 16 + col;                                    \
                float x = acc[t][r] * (SC);                                \
                (buf)[row * 64 + (c ^ ((row & 7) << 3))] = (f16)silu_f(x); \
            }                                                              \
        }

    {
        f16x8 a;
        if (lane < 16) {
            const float* rr = radial + (size_t)(e0 + lane) * 8;
            float4 ra = *(const float4*)rr;
            float4 rb = *(const float4*)(rr + 4);
            a[0] = (f16)ra.x; a[1] = (f16)ra.y; a[2] = (f16)ra.z; a[3] = (f16)ra.w;
            a[4] = (f16)rb.x; a[5] = (f16)rb.y; a[6] = (f16)rb.z; a[7] = (f16)rb.w;
        } else {
            #pragma unroll
            for (int i = 0; i < 8; i++) a[i] = (f16)0.f;
        }
        f32x4 acc[4];
        #pragma unroll
        for (int t = 0; t < 4; t++)
            acc[t] = __builtin_amdgcn_mfma_f32_16x16x32_f16(a, LDB(t), zero, 0, 0, 0);
        STACT(actA, acc, 0.35355339059327373f)
    }
    {
        f16x8 a0 = LDA(actA, 0), a1 = LDA(actA, 1);
        f32x4 acc[4];
        #pragma unroll
        for (int t = 0; t < 4; t++) {
            acc[t] = __builtin_amdgcn_mfma_f32_16x16x32_f16(a0, LDB(4 + t * 2), zero, 0, 0, 0);
            acc[t] = __builtin_amdgcn_mfma_f32_16x16x32_f16(a1, LDB(5 + t * 2), acc[t], 0, 0, 0);
        }
        STACT(actB, acc, 0.125f)
    }
    {
        f16x8 a0 = LDA(actB, 0), a1 = LDA(actB, 1);
        f32x4 acc[4];
        #pragma unroll
        for (int t = 0; t < 4; t++) {
            acc[t] = __builtin_amdgcn_mfma_f32_16x16x32_f16(a0, LDB(12 + t * 2), zero, 0, 0, 0);
            acc[t] = __builtin_amdgcn_mfma_f32_16x16x32_f16(a1, LDB(13 + t * 2), acc[t], 0, 0, 0);
        }
        STACT(actA, acc, 0.125f)
    }
    {
        f16x8 a0 = LDA(actA, 0), a1 = LDA(actA, 1);
        #pragma unroll
        for (int tg = 0; tg < 4; tg++) {
            f32x4 acc[4];
            #pragma unroll
            for (int q = 0; q < 4; q++) {
                int t = tg * 4 + q;
                acc[q] = __builtin_amdgcn_mfma_f32_16x16x32_f16(a0, LDB(20 + t * 2), zero, 0, 0, 0);
                acc[q] = __builtin_amdgcn_mfma_f32_16x16x32_f16(a1, LDB(21 + t * 2), acc[q], 0, 0, 0);
            }
            #pragma unroll
            for (int q = 0; q < 4; q++) {
                int t = tg * 4 + q;
                #pragma unroll
                for (int r = 0; r < 4; r++) {
                    int row = kg * 4 + r;
                    int c   = t * 16 + col;
                    outT[row * 256 + (c ^ ((row & 7) << 3))] = (f16)(acc[q][r] * 0.125f);
                }
            }
        }
    }
    #pragma unroll
    for (int j = 0; j < 8; j++) {
        int li  = j * 64 + lane;
        int row = li >> 5;
        int ci  = (li & 31) * 8;
        f16x8 v = *(const f16x8*)(outT + row * 256 + (ci ^ ((row & 7) << 3)));
        *(f16x8*)(mix + (size_t)(e0 + row) * 256 + ci) = v;
    }
    #undef LDB
    #undef LDA
    #undef STACT
}

// ---------------- Kernel 3: wave-per-node gather (no LDS, no atomics) ----------
// Lane owns 8 agg features: sec = lane>>3 in
// [s | tps | Cx | Cy | Cz | Dx | Dy | Dz], m0 = (lane&7)*8.
// Per edge: 16B mix load + 32B up load (tps lanes: 96B) + ~25 VALU.
__global__ __launch_bounds__(256) void gather_kernel(
    const int* __restrict__ senders, const float* __restrict__ vectors,
    const f16* __restrict__ mix, const float* __restrict__ up2,
    const int* __restrict__ cnt, const int* __restrict__ list,
    f16* __restrict__ agg)
{
    int tid = threadIdx.x, lane = tid & 63, w = tid >> 6;
    int n = blockIdx.x * 4 + w;            // 5000*4 = 20000 exact
    if ((unsigned)n >= (unsigned)NN) return;
    int count = cnt[n];
    if (count > BCAP3) count = BCAP3;
    if (count < 0) count = 0;

    int sec = lane >> 3;
    int m0  = (lane & 7) * 8;
    // up offset for the uniform path (sec 0,5,6,7 -> s block; 2,3,4 -> ex/ey/ez)
    int upoff = (sec == 2) ? 64 + m0 : (sec == 3) ? 128 + m0
              : (sec == 4) ? 192 + m0 : m0;
    // mix quarter: sec0->A(0), sec1->B(64), sec2-4->C(128), sec5-7->D(192)
    int mq = (sec == 0) ? 0 : (sec == 1) ? 64 : (sec <= 4) ? 128 : 192;
    const float SQ3 = 1.7320508075688772f;

    float a0=0,a1=0,a2=0,a3=0,a4=0,a5=0,a6=0,a7=0;
    const int* mylist = list + (size_t)n * BCAP3;

    for (int k = 0; k < count; k++) {
        int e = mylist[k];
        if ((unsigned)e >= (unsigned)EE) e = 0;
        int snd = senders[e];
        if ((unsigned)snd >= (unsigned)NN) snd = 0;
        float vx = vectors[(size_t)e * 3 + 0];
        float vy = vectors[(size_t)e * 3 + 1];
        float vz = vectors[(size_t)e * 3 + 2];
        float l2 = vx * vx + vy * vy + vz * vz;
        float il   = (l2 > 0.f) ? rsqrtf(l2) : 0.f;
        float mask = (l2 > 0.f) ? 1.f : 0.f;

        f16x8 mv = *(const f16x8*)(mix + (size_t)e * 256 + mq + m0);
        const float* u = up2 + (size_t)snd * 256;

        if (sec != 1) {
            // geometric factor: sec 5/6/7 -> sqrt3*v_c*il (0 if l2==0); else mask
            float g = (sec == 5) ? SQ3 * vx * il
                    : (sec == 6) ? SQ3 * vy * il
                    : (sec == 7) ? SQ3 * vz * il : mask;
            const float* ub = u + upoff;
            float4 u0 = *(const float4*)(ub);
            float4 u1 = *(const float4*)(ub + 4);
            a0 += u0.x * g * (float)mv[0];
            a1 += u0.y * g * (float)mv[1];
            a2 += u0.z * g * (float)mv[2];
            a3 += u0.w * g * (float)mv[3];
            a4 += u1.x * g * (float)mv[4];
            a5 += u1.y * g * (float)mv[5];
            a6 += u1.z * g * (float)mv[6];
            a7 += u1.w * g * (float)mv[7];
        } else {
            // tps: dot(ev[m], vec) * il * mixB[m]
            float4 ex0 = *(const float4*)(u + 64  + m0);
            float4 ex1 = *(const float4*)(u + 64  + m0 + 4);
            float4 ey0 = *(const float4*)(u + 128 + m0);
            float4 ey1 = *(const float4*)(u + 128 + m0 + 4);
            float4 ez0 = *(const float4*)(u + 192 + m0);
            float4 ez1 = *(const float4*)(u + 192 + m0 + 4);
            a0 += (ex0.x * vx + ey0.x * vy + ez0.x * vz) * il * (float)mv[0];
            a1 += (ex0.y * vx + ey0.y * vy + ez0.y * vz) * il * (float)mv[1];
            a2 += (ex0.z * vx + ey0.z * vy + ez0.z * vz) * il * (float)mv[2];
            a3 += (ex0.w * vx + ey0.w * vy + ez0.w * vz) * il * (float)mv[3];
            a4 += (ex1.x * vx + ey1.x * vy + ez1.x * vz) * il * (float)mv[4];
            a5 += (ex1.y * vx + ey1.y * vy + ez1.y * vz) * il * (float)mv[5];
            a6 += (ex1.z * vx + ey1.z * vy + ez1.z * vz) * il * (float)mv[6];
            a7 += (ex1.w * vx + ey1.w * vy + ez1.w * vz) * il * (float)mv[7];
        }
    }
    f16x8 o;
    o[0] = (f16)a0; o[1] = (f16)a1; o[2] = (f16)a2; o[3] = (f16)a3;
    o[4] = (f16)a4; o[5] = (f16)a5; o[6] = (f16)a6; o[7] = (f16)a7;
    *(f16x8*)(agg + (size_t)n * 512 + lane * 8) = o;
}

// ---------------- Kernel 4: MFMA node tail (proven) ----------------
__global__ __launch_bounds__(256) void node_mfma(
    const float* __restrict__ nf, const int* __restrict__ specie,
    const f16* __restrict__ wp2, const f16* __restrict__ agg,
    float* __restrict__ out)
{
    int tid = threadIdx.x, lane = tid & 63, w = tid >> 6;
    int n0 = (blockIdx.x * 4 + w) * 16;
    if (n0 >= NN) return;
    int col = lane & 15, kg = lane >> 4;
    int myn = n0 + col;
    int mysp = specie[myn];
    if ((unsigned)mysp >= 5u) mysp = 0;
    const f32x4 zero = {0.f, 0.f, 0.f, 0.f};
    const f16x8 zv = {};

    #define LDB2(fr) (*(const f16x8*)(wp2 + ((size_t)(fr) * 64 + lane) * 8))

    f32x4 accs[8];
    #pragma unroll
    for (int t = 0; t < 8; t++) accs[t] = zero;
    #pragma unroll
    for (int kf = 0; kf < 4; kf++) {
        f16x8 a = *(const f16x8*)(agg + (size_t)myn * 512 + kf * 32 + kg * 8);
        #pragma unroll
        for (int t = 0; t < 8; t++)
            accs[t] = __builtin_amdgcn_mfma_f32_16x16x32_f16(a, LDB2(t * 4 + kf), accs[t], 0, 0, 0);
    }
    #pragma unroll
    for (int kf = 0; kf < 2; kf++) {
        const float* base = nf + (size_t)myn * 256 + kf * 32 + kg * 8;
        float4 x0 = *(const float4*)(base);
        float4 x1 = *(const float4*)(base + 4);
        f16x8 a;
        a[0] = (f16)x0.x; a[1] = (f16)x0.y; a[2] = (f16)x0.z; a[3] = (f16)x0.w;
        a[4] = (f16)x1.x; a[5] = (f16)x1.y; a[6] = (f16)x1.z; a[7] = (f16)x1.w;
        #pragma unroll
        for (int sp = 0; sp < 5; sp++) {
            f16x8 am = (mysp == sp) ? a : zv;
            #pragma unroll
            for (int t = 0; t < 8; t++)
                accs[t] = __builtin_amdgcn_mfma_f32_16x16x32_f16(am, LDB2(48 + sp * 16 + t * 2 + kf), accs[t], 0, 0, 0);
        }
    }
    float gates[4][4];
    #pragma unroll
    for (int t = 0; t < 4; t++) {
        #pragma unroll
        for (int r = 0; r < 4; r++) {
            int n = n0 + kg * 4 + r;
            out[(size_t)n * 256 + t * 16 + col] = fmaxf(silu_f(accs[t][r]), 0.f);
            gates[t][r] = silu_f(accs[4 + t][r]);
        }
    }

    #pragma unroll
    for (int c = 0; c < 3; c++) {
        f32x4 accv[4];
        #pragma unroll
        for (int t = 0; t < 4; t++) accv[t] = zero;
        #pragma unroll
        for (int kf = 0; kf < 4; kf++) {
            int off = (kf < 2) ? (128 + c * 64 + kf * 32) : (320 + c * 64 + (kf - 2) * 32);
            f16x8 a = *(const f16x8*)(agg + (size_t)myn * 512 + off + kg * 8);
            #pragma unroll
            for (int t = 0; t < 4; t++)
                accv[t] = __builtin_amdgcn_mfma_f32_16x16x32_f16(a, LDB2(32 + t * 4 + kf), accv[t], 0, 0, 0);
        }
        #pragma unroll
        for (int kf = 0; kf < 2; kf++) {
            const float* base = nf + (size_t)myn * 256 + 64 + (kf * 32 + kg * 8) * 3;
            float4 q0 = *(const float4*)(base);
            float4 q1 = *(const float4*)(base + 4);
            float4 q2 = *(const float4*)(base + 8);
            float4 q3 = *(const float4*)(base + 12);
            float4 q4 = *(const float4*)(base + 16);
            float4 q5 = *(const float4*)(base + 20);
            float qa[24] = {q0.x, q0.y, q0.z, q0.w, q1.x, q1.y, q1.z, q1.w,
                            q2.x, q2.y, q2.z, q2.w, q3.x, q3.y, q3.z, q3.w,
                            q4.x, q4.y, q4.z, q4.w, q5.x, q5.y, q5.z, q5.w};
            f16x8 a;
            #pragma unroll
            for (int i = 0; i < 8; i++) a[i] = (f16)qa[i * 3 + c];
            #pragma unroll
            for (int sp = 0; sp < 5; sp++) {
                f16x8 am = (mysp == sp) ? a : zv;
                #pragma unroll
                for (int t = 0; t < 4; t++)
                    accv[t] = __builtin_amdgcn_mfma_f32_16x16x32_f16(am, LDB2(128 + sp * 8 + t * 2 + kf), accv[t], 0, 0, 0);
            }
        }
        #pragma unroll
        for (int t = 0; t < 4; t++) {
            #pragma unroll
            for (int r = 0; r < 4; r++) {
                int n = n0 + kg * 4 + r;
                out[(size_t)n * 256 + 64 + (t * 16 + col) * 3 + c] =
                    fmaxf(gates[t][r] * accv[t][r], 0.f);
            }
        }
    }
    #undef LDB2
}

// ---------------- Kernel 4b: node tail, f32 agg (fallback path) ----------------
__global__ __launch_bounds__(256) void node_kernel_f(
    const float* __restrict__ nf, const int* __restrict__ specie,
    const float* __restrict__ Wds, const float* __restrict__ Wdv,
    const float* __restrict__ Wss, const float* __restrict__ Wsv,
    const float* __restrict__ agg, float* __restrict__ out)
{
    __shared__ float sDs[128 * 128];
    __shared__ float sDv[128 * 64];
    int tid = threadIdx.x;
    for (int i = tid; i < 128 * 128; i += 256) sDs[i] = Wds[i];
    for (int i = tid; i < 128 * 64; i += 256) sDv[i] = Wdv[i];
    __syncthreads();
    int lane = tid & 63, wv = tid >> 6;
    for (int it = 0; it < 4; it++) {
        int n = blockIdx.x * 16 + wv * 4 + it;
        const float* arow = agg + (size_t)n * 512;
        const float inv_nei = 0.25f;
        float as0 = arow[lane] * inv_nei;
        float as1 = arow[64 + lane] * inv_nei;
        float av00 = arow[128 + lane] * inv_nei;
        float av01 = arow[192 + lane] * inv_nei;
        float av02 = arow[256 + lane] * inv_nei;
        float av10 = arow[320 + lane] * inv_nei;
        float av11 = arow[384 + lane] * inv_nei;
        float av12 = arow[448 + lane] * inv_nei;
        const float* row = nf + (size_t)n * 256;
        float s   = row[lane];
        float vv0 = row[64 + lane * 3 + 0];
        float vv1 = row[64 + lane * 3 + 1];
        float vv2 = row[64 + lane * 3 + 2];

        float f0 = 0.f, f1 = 0.f, fv0 = 0.f, fv1 = 0.f, fv2 = 0.f;
        #pragma unroll 8
        for (int m = 0; m < 64; m++) {
            float am = __shfl(as0, m);
            f0 += am * sDs[m * 128 + lane];
            f1 += am * sDs[m * 128 + 64 + lane];
            float b0 = __shfl(av00, m), b1 = __shfl(av01, m), b2 = __shfl(av02, m);
            float wd = sDv[m * 64 + lane];
            fv0 += b0 * wd; fv1 += b1 * wd; fv2 += b2 * wd;
        }
        #pragma unroll 8
        for (int m = 0; m < 64; m++) {
            float am = __shfl(as1, m);
            f0 += am * sDs[(64 + m) * 128 + lane];
            f1 += am * sDs[(64 + m) * 128 + 64 + lane];
            float b0 = __shfl(av10, m), b1 = __shfl(av11, m), b2 = __shfl(av12, m);
            float wd = sDv[(64 + m) * 64 + lane];
            fv0 += b0 * wd; fv1 += b1 * wd; fv2 += b2 * wd;
        }
        const float inv2m = 0.08838834764831845f;
        f0 *= inv2m; f1 *= inv2m; fv0 *= inv2m; fv1 *= inv2m; fv2 *= inv2m;

        int sp = specie[n];
        if ((unsigned)sp >= 5u) sp = 0;
        const float* Ws = Wss + (size_t)sp * 64 * 128;
        const float* Wv = Wsv + (size_t)sp * 64 * 64;
        float g0 = 0.f, g1 = 0.f, h0 = 0.f, h1 = 0.f, h2 = 0.f;
        #pragma unroll 4
        for (int m = 0; m < 64; m++) {
            float sm = __shfl(s, m);
            g0 += sm * Ws[m * 128 + lane];
            g1 += sm * Ws[m * 128 + 64 + lane];
            float b0 = __shfl(vv0, m), b1 = __shfl(vv1, m), b2 = __shfl(vv2, m);
            float wsk = Wv[m * 64 + lane];
            h0 += b0 * wsk; h1 += b1 * wsk; h2 += b2 * wsk;
        }
        f0 += g0 * 0.125f; f1 += g1 * 0.125f;
        fv0 += h0 * 0.125f; fv1 += h1 * 0.125f; fv2 += h2 * 0.125f;

        float gs   = silu_f(f0);
        float gate = silu_f(f1);
        float* orow = out + (size_t)n * 256;
        orow[lane] = fmaxf(gs, 0.f);
        orow[64 + lane * 3 + 0] = fmaxf(gate * fv0, 0.f);
        orow[64 + lane * 3 + 1] = fmaxf(gate * fv1, 0.f);
        orow[64 + lane * 3 + 2] = fmaxf(gate * fv2, 0.f);
    }
}

// ---------------- Fallback: round-3 fused edge kernel (interleaved up layout) ----------------
__global__ __launch_bounds__(256) void edge_kernel_fb(
    const float* __restrict__ vectors, const float* __restrict__ radial,
    const int* __restrict__ senders, const int* __restrict__ receivers,
    const float* __restrict__ w1, const float* __restrict__ w2,
    const float* __restrict__ w3, const float* __restrict__ wo,
    const float* __restrict__ up, float* __restrict__ agg)
{
    __shared__ __half2 hL[32 * 256];
    __shared__ float   T[16 * 256];
    __shared__ float   sVec[256 * 3];
    __shared__ int     sSnd[256];
    __shared__ int     sRcv[256];

    int tid = threadIdx.x;
    int e = blockIdx.x * 256 + tid;
    int snd = senders[e];
    int rcv = receivers[e];
    if ((unsigned)snd >= (unsigned)NN) snd = 0;
    if ((unsigned)rcv >= (unsigned)NN) rcv = 0;
    float4 ra = *(const float4*)(radial + (size_t)e * 8);
    float4 rb = *(const float4*)(radial + (size_t)e * 8 + 4);
    float vx = vectors[(size_t)e * 3 + 0];
    float vy = vectors[(size_t)e * 3 + 1];
    float vz = vectors[(size_t)e * 3 + 2];
    sSnd[tid] = snd; sRcv[tid] = rcv;
    sVec[tid * 3 + 0] = vx; sVec[tid * 3 + 1] = vy; sVec[tid * 3 + 2] = vz;
    float len2 = vx * vx + vy * vy + vz * vz;
    float mask = (len2 > 0.f) ? 1.f : 0.f;

    {
        float a[64];
        #pragma unroll
        for (int j = 0; j < 64; j++) {
            float acc = ra.x * w1[j]       + ra.y * w1[64 + j]
                      + ra.z * w1[128 + j] + ra.w * w1[192 + j]
                      + rb.x * w1[256 + j] + rb.y * w1[320 + j]
                      + rb.z * w1[384 + j] + rb.w * w1[448 + j];
            a[j] = silu_f(acc * 0.35355339059327373f);
        }
        #pragma unroll
        for (int jp = 0; jp < 32; jp++)
            hL[jp * 256 + tid] = __floats2half2_rn(a[2 * jp], a[2 * jp + 1]);
    }
    {
        float acc[64];
        #pragma unroll
        for (int j = 0; j < 64; j++) acc[j] = 0.f;
        #pragma unroll 2
        for (int kp = 0; kp < 32; kp++) {
            float2 hf = __half22float2(hL[kp * 256 + tid]);
            const float* wr0 = w2 + (size_t)(2 * kp) * 64;
            const float* wr1 = w2 + (size_t)(2 * kp + 1) * 64;
            #pragma unroll
            for (int j = 0; j < 64; j++) acc[j] += hf.x * wr0[j] + hf.y * wr1[j];
        }
        #pragma unroll
        for (int jp = 0; jp < 32; jp++)
            hL[jp * 256 + tid] = __floats2half2_rn(silu_f(acc[2 * jp] * 0.125f),
                                                   silu_f(acc[2 * jp + 1] * 0.125f));
    }
    {
        float acc[64];
        #pragma unroll
        for (int j = 0; j < 64; j++) acc[j] = 0.f;
        #pragma unroll 2
        for (int kp = 0; kp < 32; kp++) {
            float2 hf = __half22float2(hL[kp * 256 + tid]);
            const float* wr0 = w3 + (size_t)(2 * kp) * 64;
            const float* wr1 = w3 + (size_t)(2 * kp + 1) * 64;
            #pragma unroll
            for (int j = 0; j < 64; j++) acc[j] += hf.x * wr0[j] + hf.y * wr1[j];
        }
        #pragma unroll
        for (int jp = 0; jp < 32; jp++)
            hL[jp * 256 + tid] = __floats2half2_rn(silu_f(acc[2 * jp] * 0.125f),
                                                   silu_f(acc[2 * jp + 1] * 0.125f));
    }

    int lane  = tid & 63;
    int wbase = tid & 192;
    int f = lane & 15;
    int g = lane >> 4;

    #define COMPUTE_CHUNK(c, ao)                                                \
        {                                                                       \
            _Pragma("unroll")                                                   \
            for (int j = 0; j < 16; j++) ao[j] = 0.f;                           \
            _Pragma("unroll 4")                                                 \
            for (int kp = 0; kp < 32; kp++) {                                   \
                float2 hf = __half22float2(hL[kp * 256 + tid]);                 \
                const float* wr0 = wo + (size_t)(2 * kp) * 256 + (c) * 16;      \
                const float* wr1 = wo + (size_t)(2 * kp + 1) * 256 + (c) * 16;  \
                _Pragma("unroll")                                               \
                for (int j = 0; j < 16; j++)                                    \
                    ao[j] += hf.x * wr0[j] + hf.y * wr1[j];                     \
            }                                                                   \
            _Pragma("unroll")                                                   \
            for (int j = 0; j < 16; j++) ao[j] *= 0.125f * mask;                \
        }

    #define WRITE_T(ao)                                                         \
        __syncthreads();                                                        \
        _Pragma("unroll")                                                       \
        for (int j = 0; j < 16; j++) T[j * 256 + (tid ^ (2 * j))] = ao[j];      \
        __syncthreads();

    for (int c = 0; c < 4; c++) {
        float ao[16];
        COMPUTE_CHUNK(c, ao)
        WRITE_T(ao)
        for (int el = 0; el < 16; el++) {
            int col = wbase + el * 4 + g;
            int s_ = sSnd[col], rc = sRcv[col];
            float mx = T[f * 256 + (col ^ (2 * f))];
            int jf = c * 16 + f;
            atomicAdd(agg + (size_t)rc * 512 + jf, up[(size_t)s_ * 256 + jf] * mx);
        }
    }
    for (int c = 4; c < 8; c++) {
        float ao[16];
        COMPUTE_CHUNK(c, ao)
        WRITE_T(ao)
        for (int el = 0; el < 16; el++) {
            int col = wbase + el * 4 + g;
            int s_ = sSnd[col], rc = sRcv[col];
            float wx = sVec[col * 3 + 0], wy = sVec[col * 3 + 1], wz = sVec[col * 3 + 2];
            float l2 = wx * wx + wy * wy + wz * wz;
            float il = (l2 > 0.f) ? rsqrtf(l2) : 0.f;
            float mx = T[f * 256 + (col ^ (2 * f))];
            int m = (c - 4) * 16 + f;
            const float* ev = up + (size_t)s_ * 256 + 64 + m * 3;
            float dot = ev[0] * wx + ev[1] * wy + ev[2] * wz;
            atomicAdd(agg + (size_t)rc * 512 + 64 + m, dot * il * mx);
        }
    }
    for (int c = 8; c < 12; c++) {
        float ao[16];
        COMPUTE_CHUNK(c, ao)
        WRITE_T(ao)
        for (int el = 0; el < 16; el++) {
            int col = wbase + el * 4 + g;
            int s_ = sSnd[col], rc = sRcv[col];
            float mx = T[f * 256 + (col ^ (2 * f))];
            int m = (c - 8) * 16 + f;
            const float* ev = up + (size_t)s_ * 256 + 64 + m * 3;
            float* ag = agg + (size_t)rc * 512 + 128 + m;
            atomicAdd(ag + 0,   ev[0] * mx);
            atomicAdd(ag + 64,  ev[1] * mx);
            atomicAdd(ag + 128, ev[2] * mx);
        }
    }
    for (int c = 12; c < 16; c++) {
        float ao[16];
        COMPUTE_CHUNK(c, ao)
        WRITE_T(ao)
        for (int el = 0; el < 16; el++) {
            int col = wbase + el * 4 + g;
            int s_ = sSnd[col], rc = sRcv[col];
            float wx = sVec[col * 3 + 0], wy = sVec[col * 3 + 1], wz = sVec[col * 3 + 2];
            float l2 = wx * wx + wy * wy + wz * wz;
            float il = (l2 > 0.f) ? rsqrtf(l2) : 0.f;
            float mx = T[f * 256 + (col ^ (2 * f))];
            int m = (c - 12) * 16 + f;
            float sc = up[(size_t)s_ * 256 + m] * 1.7320508075688772f * il * mx;
            float* ag = agg + (size_t)rc * 512 + 320 + m;
            atomicAdd(ag + 0,   sc * wx);
            atomicAdd(ag + 64,  sc * wy);
            atomicAdd(ag + 128, sc * wz);
        }
    }
    #undef COMPUTE_CHUNK
    #undef WRITE_T
}

extern "C" void kernel_launch(void* const* d_in, const int* in_sizes, int n_in,
                              void* d_out, int out_size, void* d_ws, size_t ws_size,
                              hipStream_t stream) {
    const float* vectors     = (const float*)d_in[0];
    const float* node_feats  = (const float*)d_in[1];
    const int*   node_specie = (const int*)d_in[2];
    const float* radial      = (const float*)d_in[3];
    const int*   senders     = (const int*)d_in[4];
    const int*   receivers   = (const int*)d_in[5];
    const float* W_up_s      = (const float*)d_in[6];
    const float* W_up_v      = (const float*)d_in[7];
    const float* mlp_w1      = (const float*)d_in[8];
    const float* mlp_w2      = (const float*)d_in[9];
    const float* mlp_w3      = (const float*)d_in[10];
    const float* mlp_wo      = (const float*)d_in[11];
    const float* W_skip_s    = (const float*)d_in[12];
    const float* W_skip_v    = (const float*)d_in[13];
    const float* W_down_s    = (const float*)d_in[14];
    const float* W_down_v    = (const float*)d_in[15];
    float* out = (float*)d_out;

    // workspace: up | agg-region (41MB f32-sized; primary uses f16 agg + cnt/list
    //            inside the unused upper half) | wpack | wp2 | mix
    float* up   = (float*)d_ws;                       // 20.48 MB
    float* aggf = up + (size_t)NN * 256;              // 40.96 MB region (fallback f32 agg)
    f16*   aggh = (f16*)aggf;                         // primary f16 agg: 20.48 MB
    int*   cnt  = (int*)((char*)aggf + 21 * 1024 * 1024);      // 80 KB
    int*   list = cnt + 20480;                                  // 5.12 MB (ends < 41 MB)
    uintptr_t wp_addr = ((uintptr_t)(aggf + (size_t)NN * 512) + 255) & ~(uintptr_t)255;
    f16* wpack = (f16*)wp_addr;                       // 26.6 KB
    f16* wp2   = wpack + (size_t)52 * 64 * 8;         // 172 KB
    uintptr_t mix_addr = ((uintptr_t)(wp2 + (size_t)168 * 64 * 8) + 255) & ~(uintptr_t)255;
    f16* mix = (f16*)mix_addr;                        // 163.84 MB
    size_t required = (size_t)(mix_addr + (size_t)EE * 256 * sizeof(f16)
                               - (uintptr_t)d_ws);

    if (ws_size >= required) {
        // ---- split pipeline: mix materialization + bucketed no-atomic gather ----
        hipMemsetAsync(cnt, 0, NN * sizeof(int), stream);
        pack_kernel<<<13, 256, 0, stream>>>(mlp_w1, mlp_w2, mlp_w3, mlp_wo, wpack);
        pack2_kernel<<<42, 256, 0, stream>>>(W_down_s, W_down_v, W_skip_s, W_skip_v, wp2);
        up_kernel<<<NN / 16, 256, 0, stream>>>(node_feats, W_up_s, W_up_v, up, 1);
        bucket_kernel<<<EE / 256, 256, 0, stream>>>(receivers, cnt, list);
        mlp_mix<<<EE / 64, 256, 0, stream>>>(radial, wpack, mix);
        gather_kernel<<<NN / 4, 256, 0, stream>>>(senders, vectors, mix, up,
            cnt, list, aggh);
        node_mfma<<<(NN / 16 + 3) / 4, 256, 0, stream>>>(node_feats, node_specie,
            wp2, aggh, out);
    } else {
        // ---- fallback: round-3 fused atomic path (f32 agg) ----
        hipMemsetAsync(aggf, 0, (size_t)NN * 512 * sizeof(float), stream);
        up_kernel<<<NN / 16, 256, 0, stream>>>(node_feats, W_up_s, W_up_v, up, 0);
        edge_kernel_fb<<<EE / 256, 256, 0, stream>>>(
            vectors, radial, senders, receivers,
            mlp_w1, mlp_w2, mlp_w3, mlp_wo, up, aggf);
        node_kernel_f<<<NN / 16, 256, 0, stream>>>(node_feats, node_specie,
            W_down_s, W_down_v, W_skip_s, W_skip_v, aggf, out);
    }
}